// Round 10
// baseline (162.052 us; speedup 1.0000x reference)
//
#include <hip/hip_runtime.h>
#include <hip/hip_bf16.h>
#include <math.h>

#define F_IN    256
#define R_REL   8
#define H_HEADS 4
#define U_DIM   64
#define B_BASES 4
#define C_TOT   (R_REL * H_HEADS)   // 32
#define LRELU   0.01f
#define SLOT_CAP 64                  // max degree capacity (Poisson(16): P(>64) ~ 1e-16)

typedef __attribute__((ext_vector_type(8))) short short8;
typedef __attribute__((ext_vector_type(4))) float f32x4;

__device__ __forceinline__ unsigned short f2bf(float f) {
    unsigned int u = __float_as_uint(f);
    u = (u + 0x7FFF + ((u >> 16) & 1)) >> 16;   // RNE
    return (unsigned short)u;
}
__device__ __forceinline__ float bf2f_lo(unsigned int v) { return __uint_as_float(v << 16); }
__device__ __forceinline__ float bf2f_hi(unsigned int v) { return __uint_as_float(v & 0xFFFF0000u); }

// -----------------------------------------------------------------------------
// K1: prep. 79 blocks: all zero a chunk of counts; blocks 0..31 also build Wt.
// Wt row j (j<256): basis[b=j&3][f][u=j>>2]  (zb interleaved col order);
// rows 256..287=Pq[c], 288..319=Pk[c].
// -----------------------------------------------------------------------------
__global__ __launch_bounds__(256) void prep_all(const float* __restrict__ basis,
                                                const float* __restrict__ coeff,
                                                const float* __restrict__ attn_q,
                                                const float* __restrict__ attn_k,
                                                unsigned short* __restrict__ Wt,
                                                int* __restrict__ counts,
                                                int n_nodes) {
    int i = blockIdx.x * 256 + threadIdx.x;
    if (i < n_nodes) counts[i] = 0;
    if (blockIdx.x >= C_TOT) return;

    __shared__ float aq[64], ak[64];
    int c = blockIdx.x;                   // 0..31
    int f = threadIdx.x;                  // 0..255
    if (f < 64) {
        aq[f] = attn_q[c * 64 + f];
        ak[f] = attn_k[c * 64 + f];
    }
    __syncthreads();

    #pragma unroll
    for (int j = 0; j < 8; ++j) {
        int nn = c * 8 + j;               // 0..255
        int b = nn & 3, u = nn >> 2;
        Wt[(size_t)nn * 256 + f] = f2bf(basis[(size_t)b * (F_IN * U_DIM) + (size_t)f * U_DIM + u]);
    }

    float sq = 0.f, sk = 0.f;
    #pragma unroll
    for (int b = 0; b < B_BASES; ++b) {
        float cb = coeff[c * 4 + b];
        const float* bp = basis + (size_t)b * (F_IN * U_DIM) + (size_t)f * U_DIM;
        float dq = 0.f, dk = 0.f;
        #pragma unroll
        for (int u = 0; u < 64; ++u) {
            float v = bp[u];
            dq += v * aq[u];
            dk += v * ak[u];
        }
        sq += cb * dq;
        sk += cb * dk;
    }
    Wt[(size_t)(256 + c) * 256 + f] = f2bf(sq);
    Wt[(size_t)(288 + c) * 256 + f] = f2bf(sk);
}

// -----------------------------------------------------------------------------
// K2: single-pass MFMA GEMM over all 320 output cols + edge scatter.
// 1-D grid: blocks [0, n_m_blocks): gemm (BM=64, BN=320, BK=64); blocks
// [n_m_blocks, +32): edge scatter.
// GEMM stages x fp32 -> bf16 LDS directly (no xb buffer). 4 waves: wr=m half
// (32 rows), wc=col half (160 cols = 10 tiles). Cols <256 -> zb bf16
// (interleaved via permuted Wt); cols >=256 -> qk fp32.
// -----------------------------------------------------------------------------
__global__ __launch_bounds__(256) void gemm_all(const float* __restrict__ x,
                                                const unsigned short* __restrict__ Wt,
                                                unsigned short* __restrict__ zb,
                                                float* __restrict__ qk,
                                                const int* __restrict__ src,
                                                const int* __restrict__ dst,
                                                const int* __restrict__ rel,
                                                int* __restrict__ counts,
                                                unsigned int* __restrict__ slots,
                                                int nrows, int E, int n_m_blocks) {
    if ((int)blockIdx.x >= n_m_blocks) {
        int sb = blockIdx.x - n_m_blocks;           // 0..31
        int stride = 32 * 256;
        for (int i = sb * 256 + threadIdx.x; i < E; i += stride) {
            int d = dst[i];
            int pos = atomicAdd(&counts[d], 1);
            if (pos < SLOT_CAP)
                slots[(size_t)d * SLOT_CAP + pos] = (unsigned)src[i] | ((unsigned)rel[i] << 20);
        }
        return;
    }

    __shared__ unsigned short Al[64 * 72];    // 9 KB
    __shared__ unsigned short Bl[320 * 72];   // 45 KB

    const int tid  = threadIdx.x;
    const int wave = tid >> 6;
    const int lane = tid & 63;
    const int wr   = wave >> 1;     // m half (32 rows)
    const int wc   = wave & 1;      // col half (160 cols)
    const int m0   = blockIdx.x * 64;
    const int l15  = lane & 15;
    const int quad = lane >> 4;

    f32x4 acc[2][10];
    #pragma unroll
    for (int t = 0; t < 2; ++t)
        #pragma unroll
        for (int s = 0; s < 10; ++s)
            acc[t][s] = (f32x4){0.f, 0.f, 0.f, 0.f};

    for (int k0 = 0; k0 < 256; k0 += 64) {
        // stage A: 64 rows x 64 k, fp32 -> bf16 (4 float4 per thread)
        #pragma unroll
        for (int p = 0; p < 4; ++p) {
            int idx = p * 256 + tid;
            int row = idx >> 4;          // 0..63
            int cg  = idx & 15;          // float4 group (4 floats)
            int gr  = m0 + row;
            float4 v = make_float4(0.f, 0.f, 0.f, 0.f);
            if (gr < nrows) v = *(const float4*)&x[(size_t)gr * 256 + k0 + cg * 4];
            ushort4 o;
            o.x = f2bf(v.x); o.y = f2bf(v.y); o.z = f2bf(v.z); o.w = f2bf(v.w);
            *(ushort4*)&Al[row * 72 + cg * 4] = o;
        }
        // stage B: 320 rows x 64 k (10 uint4 per thread)
        #pragma unroll
        for (int p = 0; p < 10; ++p) {
            int idx = p * 256 + tid;
            int row = idx >> 3;          // 0..319
            int cg  = idx & 7;           // 8-short group
            uint4 v = *(const uint4*)&Wt[(size_t)row * 256 + k0 + cg * 8];
            *(uint4*)&Bl[row * 72 + cg * 8] = v;
        }
        __syncthreads();

        #pragma unroll
        for (int ks = 0; ks < 64; ks += 32) {
            short8 afr[2];
            #pragma unroll
            for (int t = 0; t < 2; ++t)
                afr[t] = *(short8*)&Al[(wr * 32 + t * 16 + l15) * 72 + ks + quad * 8];
            #pragma unroll
            for (int s = 0; s < 10; ++s) {
                short8 bfr = *(short8*)&Bl[(wc * 160 + s * 16 + l15) * 72 + ks + quad * 8];
                #pragma unroll
                for (int t = 0; t < 2; ++t)
                    acc[t][s] = __builtin_amdgcn_mfma_f32_16x16x32_bf16(afr[t], bfr, acc[t][s], 0, 0, 0);
            }
        }
        __syncthreads();
    }

    #pragma unroll
    for (int t = 0; t < 2; ++t) {
        #pragma unroll
        for (int s = 0; s < 10; ++s) {
            int n = wc * 160 + s * 16 + l15;           // output col 0..319
            #pragma unroll
            for (int reg = 0; reg < 4; ++reg) {
                int m = m0 + wr * 32 + t * 16 + quad * 4 + reg;
                if (m < nrows) {
                    float v = acc[t][s][reg];
                    if (n < 256) zb[(size_t)m * 256 + n] = f2bf(v);
                    else         qk[(size_t)m * 64 + (n - 256)] = v;
                }
            }
        }
    }
}

// -----------------------------------------------------------------------------
// K3: agg (R6 best config). One wave per dst node; degree <= 64.
//  pass A: one edge/lane; denominators via shfl_xor; each lane computes its
//          edge's folded weights g[4] and parks (g, src) in wave-private LDS.
//  pass B: 8 edges x 8 lanes/edge; coalesced 128 B chunk reads of the bf16
//          z-row; 3-round shfl_xor over edge slots; float2 stores.
// -----------------------------------------------------------------------------
__global__ __launch_bounds__(256) void agg_kernel(const unsigned short* __restrict__ zb,
                                                  const float* __restrict__ qk,
                                                  const float* __restrict__ coeff,
                                                  const unsigned int* __restrict__ slots,
                                                  const int* __restrict__ counts,
                                                  float* __restrict__ out,
                                                  int n_nodes) {
    __shared__ float cf[128];
    __shared__ float4 gsh[4][64];
    __shared__ int    ssh[4][64];
    if (threadIdx.x < 128) cf[threadIdx.x] = coeff[threadIdx.x];
    __syncthreads();

    int wv   = threadIdx.x >> 6;
    int n    = blockIdx.x * 4 + wv;
    int lane = threadIdx.x & 63;
    if (n >= n_nodes) return;

    int cnt = counts[n];
    if (cnt > SLOT_CAP) cnt = SLOT_CAP;
    const unsigned int* sl = slots + (size_t)n * SLOT_CAP;

    // ---- pass A
    float e0 = 0.f, e1 = 0.f, e2 = 0.f, e3 = 0.f;
    int s_edge = 0, r_edge = 0;
    if (lane < cnt) {
        unsigned p = sl[lane];
        s_edge = (int)(p & 0xFFFFFu);
        r_edge = (int)(p >> 20);
        float4 q  = *(const float4*)&qk[(size_t)s_edge * 64 + r_edge * 4];
        float4 kv = *(const float4*)&qk[(size_t)n * 64 + 32 + r_edge * 4];
        float l0 = q.x + kv.x, l1 = q.y + kv.y, l2 = q.z + kv.z, l3 = q.w + kv.w;
        l0 = (l0 > 0.f) ? l0 : LRELU * l0;
        l1 = (l1 > 0.f) ? l1 : LRELU * l1;
        l2 = (l2 > 0.f) ? l2 : LRELU * l2;
        l3 = (l3 > 0.f) ? l3 : LRELU * l3;
        e0 = __expf(l0); e1 = __expf(l1); e2 = __expf(l2); e3 = __expf(l3);
    }
    float d0 = e0, d1 = e1, d2 = e2, d3 = e3;
    #pragma unroll
    for (int off = 32; off; off >>= 1) {
        d0 += __shfl_xor(d0, off);
        d1 += __shfl_xor(d1, off);
        d2 += __shfl_xor(d2, off);
        d3 += __shfl_xor(d3, off);
    }
    if (lane < cnt) {
        float a0 = e0 * ((d0 > 0.f) ? 0.25f / d0 : 0.f);
        float a1 = e1 * ((d1 > 0.f) ? 0.25f / d1 : 0.f);
        float a2 = e2 * ((d2 > 0.f) ? 0.25f / d2 : 0.f);
        float a3 = e3 * ((d3 > 0.f) ? 0.25f / d3 : 0.f);
        const float* c0 = &cf[(r_edge * 4 + 0) * 4];
        const float* c1 = &cf[(r_edge * 4 + 1) * 4];
        const float* c2 = &cf[(r_edge * 4 + 2) * 4];
        const float* c3 = &cf[(r_edge * 4 + 3) * 4];
        float4 g4;
        g4.x = a0 * c0[0] + a1 * c1[0] + a2 * c2[0] + a3 * c3[0];
        g4.y = a0 * c0[1] + a1 * c1[1] + a2 * c2[1] + a3 * c3[1];
        g4.z = a0 * c0[2] + a1 * c1[2] + a2 * c2[2] + a3 * c3[2];
        g4.w = a0 * c0[3] + a1 * c1[3] + a2 * c2[3] + a3 * c3[3];
        gsh[wv][lane] = g4;
        ssh[wv][lane] = s_edge;
    }
    // wave-private LDS region: no barrier needed

    // ---- pass B
    int es = lane >> 3;
    int g  = lane & 7;
    float acc[4][2];
    #pragma unroll
    for (int v = 0; v < 4; ++v) { acc[v][0] = 0.f; acc[v][1] = 0.f; }

    for (int base = 0; base < cnt; base += 8) {
        int i = base + es;
        if (i < cnt) {
            float4 g4 = gsh[wv][i];
            int s = ssh[wv][i];
            const unsigned short* zr = zb + (size_t)s * 256 + g * 8;
            #pragma unroll
            for (int v = 0; v < 4; ++v) {
                uint4 z4 = *(const uint4*)(zr + v * 64);
                acc[v][0] += g4.x * bf2f_lo(z4.x) + g4.y * bf2f_hi(z4.x) +
                             g4.z * bf2f_lo(z4.y) + g4.w * bf2f_hi(z4.y);
                acc[v][1] += g4.x * bf2f_lo(z4.z) + g4.y * bf2f_hi(z4.z) +
                             g4.z * bf2f_lo(z4.w) + g4.w * bf2f_hi(z4.w);
            }
        }
    }

    #pragma unroll
    for (int v = 0; v < 4; ++v) {
        #pragma unroll
        for (int j = 0; j < 2; ++j) {
            acc[v][j] += __shfl_xor(acc[v][j], 8);
            acc[v][j] += __shfl_xor(acc[v][j], 16);
            acc[v][j] += __shfl_xor(acc[v][j], 32);
        }
    }
    if (es == 0) {
        #pragma unroll
        for (int v = 0; v < 4; ++v) {
            float2 o = make_float2(acc[v][0], acc[v][1]);
            *(float2*)&out[(size_t)n * 64 + v * 16 + g * 2] = o;
        }
    }
}

// -----------------------------------------------------------------------------
extern "C" void kernel_launch(void* const* d_in, const int* in_sizes, int n_in,
                              void* d_out, int out_size, void* d_ws, size_t ws_size,
                              hipStream_t stream) {
    const float* x      = (const float*)d_in[0];
    const float* basis  = (const float*)d_in[1];
    const float* coeff  = (const float*)d_in[2];
    const float* attn_q = (const float*)d_in[3];
    const float* attn_k = (const float*)d_in[4];
    const int*   src    = (const int*)d_in[5];
    const int*   dst    = (const int*)d_in[6];
    const int*   rel    = (const int*)d_in[7];
    float* out = (float*)d_out;

    const int n_nodes = in_sizes[0] / F_IN;   // 20000
    const int E       = in_sizes[5];          // 320000

    char* ws = (char*)d_ws;
    size_t off = 0;
    auto alloc = [&](size_t bytes) -> void* {
        void* p = ws + off;
        off += bytes;
        off = (off + 255) & ~(size_t)255;
        return p;
    };
    unsigned short* Wt   = (unsigned short*)alloc((size_t)320 * 256 * 2);       // 160 KB
    unsigned short* zb   = (unsigned short*)alloc((size_t)n_nodes * 256 * 2);   // 10.2 MB
    float* qk            = (float*)alloc((size_t)n_nodes * 64 * 4);             // 5.1 MB
    unsigned int* slots  = (unsigned int*)alloc((size_t)n_nodes * SLOT_CAP * 4);// 5.1 MB
    int* counts          = (int*)alloc((size_t)n_nodes * 4);

    // K1: Wt build + counts zeroing (79 blocks)
    int n_prep_blocks = (n_nodes + 255) / 256;   // 79 >= 32
    prep_all<<<n_prep_blocks, 256, 0, stream>>>(basis, coeff, attn_q, attn_k, Wt,
                                                counts, n_nodes);

    // K2: single-pass gemm (313 blocks) + scatter (32 blocks)
    int n_m_blocks = (n_nodes + 63) / 64;        // 313
    gemm_all<<<n_m_blocks + 32, 256, 0, stream>>>(x, Wt, zb, qk, src, dst, rel,
                                                  counts, slots, n_nodes, E, n_m_blocks);

    // K3: fused softmax + aggregation
    agg_kernel<<<(n_nodes + 3) / 4, 256, 0, stream>>>(zb, qk, coeff, slots, counts, out, n_nodes);
}

// Round 11
// 142.632 us; speedup vs baseline: 1.1362x; 1.1362x over previous
//
#include <hip/hip_runtime.h>
#include <hip/hip_bf16.h>
#include <math.h>

#define F_IN    256
#define R_REL   8
#define H_HEADS 4
#define U_DIM   64
#define B_BASES 4
#define C_TOT   (R_REL * H_HEADS)   // 32
#define LRELU   0.01f
#define SLOT_CAP 64                  // max degree capacity (Poisson(16): P(>64) ~ 1e-16)

typedef __attribute__((ext_vector_type(8))) short short8;
typedef __attribute__((ext_vector_type(4))) float f32x4;

__device__ __forceinline__ unsigned short f2bf(float f) {
    unsigned int u = __float_as_uint(f);
    u = (u + 0x7FFF + ((u >> 16) & 1)) >> 16;   // RNE
    return (unsigned short)u;
}
__device__ __forceinline__ float bf2f_lo(unsigned int v) { return __uint_as_float(v << 16); }
__device__ __forceinline__ float bf2f_hi(unsigned int v) { return __uint_as_float(v & 0xFFFF0000u); }

// -----------------------------------------------------------------------------
// K1: fused prep (R6 config).
//  blocks [0, n_cast_blocks): cast x->bf16 (4 elems/thread) + zero counts
//  blocks [n_cast_blocks, +32): build Wt (permuted basis rows + Pq/Pk rows)
// Wt row j (j<256): basis[b=j&3][f][u=j>>2]  -> GEMM output col j == zb
// interleaved col (u*4+b). Rows 256..287=Pq[c], 288..319=Pk[c].
// -----------------------------------------------------------------------------
__global__ __launch_bounds__(256) void prep_all(const float* __restrict__ x,
                                                unsigned short* __restrict__ xb,
                                                int total4,
                                                int* __restrict__ counts,
                                                int n_nodes,
                                                const float* __restrict__ basis,
                                                const float* __restrict__ coeff,
                                                const float* __restrict__ attn_q,
                                                const float* __restrict__ attn_k,
                                                unsigned short* __restrict__ Wt,
                                                int n_cast_blocks) {
    if (blockIdx.x < (unsigned)n_cast_blocks) {
        int i = blockIdx.x * 256 + threadIdx.x;
        if (i < n_nodes) counts[i] = 0;
        if (i >= total4) return;
        float4 v = *(const float4*)&x[(size_t)i * 4];
        ushort4 o;
        o.x = f2bf(v.x); o.y = f2bf(v.y); o.z = f2bf(v.z); o.w = f2bf(v.w);
        *(ushort4*)&xb[(size_t)i * 4] = o;
        return;
    }

    __shared__ float aq[64], ak[64];
    int c = blockIdx.x - n_cast_blocks;   // 0..31
    int f = threadIdx.x;                  // 0..255
    if (f < 64) {
        aq[f] = attn_q[c * 64 + f];
        ak[f] = attn_k[c * 64 + f];
    }
    __syncthreads();

    #pragma unroll
    for (int j = 0; j < 8; ++j) {
        int nn = c * 8 + j;               // 0..255
        int b = nn & 3, u = nn >> 2;
        Wt[(size_t)nn * 256 + f] = f2bf(basis[(size_t)b * (F_IN * U_DIM) + (size_t)f * U_DIM + u]);
    }

    float sq = 0.f, sk = 0.f;
    #pragma unroll
    for (int b = 0; b < B_BASES; ++b) {
        float cb = coeff[c * 4 + b];
        const float* bp = basis + (size_t)b * (F_IN * U_DIM) + (size_t)f * U_DIM;
        float dq = 0.f, dk = 0.f;
        #pragma unroll
        for (int u = 0; u < 64; ++u) {
            float v = bp[u];
            dq += v * aq[u];
            dk += v * ak[u];
        }
        sq += cb * dq;
        sk += cb * dk;
    }
    Wt[(size_t)(256 + c) * 256 + f] = f2bf(sq);
    Wt[(size_t)(288 + c) * 256 + f] = f2bf(sk);
}

// -----------------------------------------------------------------------------
// K2: MFMA GEMM + scatter. grid (157, 4):
//  y=0,1: y-slices, BN=128 (cols y*128..+128), BM=128, BK=64, acc[4][4];
//         A staged once per block (2x reuse vs R6's 4 slices).
//  y=2:   qk slice, BN=64 (cols 256..319) — R6 config.
//  y=3:   edge scatter only.
// Stores identical per-element pattern to R6 (no operand swap).
// -----------------------------------------------------------------------------
__global__ __launch_bounds__(256) void gemm_scatter(const unsigned short* __restrict__ xb,
                                                    const unsigned short* __restrict__ Wt,
                                                    unsigned short* __restrict__ zb,
                                                    float* __restrict__ qk,
                                                    const int* __restrict__ src,
                                                    const int* __restrict__ dst,
                                                    const int* __restrict__ rel,
                                                    int* __restrict__ counts,
                                                    unsigned int* __restrict__ slots,
                                                    int nrows, int E) {
    if (blockIdx.y == 3) {
        int stride = gridDim.x * 256;
        int base = blockIdx.x * 256 + threadIdx.x;
        for (int i = base; i < E; i += stride) {
            int d = dst[i];
            int pos = atomicAdd(&counts[d], 1);
            if (pos < SLOT_CAP)
                slots[(size_t)d * SLOT_CAP + pos] = (unsigned)src[i] | ((unsigned)rel[i] << 20);
        }
        return;
    }

    __shared__ unsigned short Al[128 * 72];   // 18 KB
    __shared__ unsigned short Bl[128 * 72];   // 18 KB (y-slices use all; qk uses half)

    const int tid  = threadIdx.x;
    const int wave = tid >> 6;
    const int lane = tid & 63;
    const int wr   = wave >> 1;
    const int wc   = wave & 1;
    const int m0   = blockIdx.x * 128;
    const int bb   = blockIdx.y;    // 0,1: y-slices; 2: qk
    const int l15  = lane & 15;
    const int quad = lane >> 4;

    if (bb < 2) {
        f32x4 acc[4][4];
        #pragma unroll
        for (int t = 0; t < 4; ++t)
            #pragma unroll
            for (int s = 0; s < 4; ++s)
                acc[t][s] = (f32x4){0.f, 0.f, 0.f, 0.f};

        for (int k0 = 0; k0 < 256; k0 += 64) {
            #pragma unroll
            for (int p = 0; p < 4; ++p) {
                int idx = p * 256 + tid;
                int row = idx >> 3;
                int cg  = idx & 7;
                int gr  = m0 + row;
                uint4 v = make_uint4(0, 0, 0, 0);
                if (gr < nrows) v = *(const uint4*)&xb[(size_t)gr * 256 + k0 + cg * 8];
                *(uint4*)&Al[row * 72 + cg * 8] = v;
            }
            #pragma unroll
            for (int p = 0; p < 4; ++p) {
                int idx = p * 256 + tid;
                int row = idx >> 3;
                int cg  = idx & 7;
                uint4 v = *(const uint4*)&Wt[(size_t)(bb * 128 + row) * 256 + k0 + cg * 8];
                *(uint4*)&Bl[row * 72 + cg * 8] = v;
            }
            __syncthreads();

            #pragma unroll
            for (int ks = 0; ks < 64; ks += 32) {
                short8 bfr[4];
                #pragma unroll
                for (int s = 0; s < 4; ++s)
                    bfr[s] = *(short8*)&Bl[(wc * 64 + s * 16 + l15) * 72 + ks + quad * 8];
                #pragma unroll
                for (int t = 0; t < 4; ++t) {
                    short8 afr = *(short8*)&Al[(wr * 64 + t * 16 + l15) * 72 + ks + quad * 8];
                    #pragma unroll
                    for (int s = 0; s < 4; ++s)
                        acc[t][s] = __builtin_amdgcn_mfma_f32_16x16x32_bf16(afr, bfr[s], acc[t][s], 0, 0, 0);
                }
            }
            __syncthreads();
        }

        #pragma unroll
        for (int t = 0; t < 4; ++t) {
            #pragma unroll
            for (int s = 0; s < 4; ++s) {
                int c_local = bb * 128 + wc * 64 + s * 16 + l15;   // 0..255
                #pragma unroll
                for (int reg = 0; reg < 4; ++reg) {
                    int m = m0 + wr * 64 + t * 16 + quad * 4 + reg;
                    if (m < nrows)
                        zb[(size_t)m * 256 + c_local] = f2bf(acc[t][s][reg]);
                }
            }
        }
    } else {
        // qk slice (R6 config, BN=64)
        f32x4 acc[4][2];
        #pragma unroll
        for (int t = 0; t < 4; ++t)
            #pragma unroll
            for (int s = 0; s < 2; ++s)
                acc[t][s] = (f32x4){0.f, 0.f, 0.f, 0.f};

        for (int k0 = 0; k0 < 256; k0 += 64) {
            #pragma unroll
            for (int p = 0; p < 4; ++p) {
                int idx = p * 256 + tid;
                int row = idx >> 3;
                int cg  = idx & 7;
                int gr  = m0 + row;
                uint4 v = make_uint4(0, 0, 0, 0);
                if (gr < nrows) v = *(const uint4*)&xb[(size_t)gr * 256 + k0 + cg * 8];
                *(uint4*)&Al[row * 72 + cg * 8] = v;
            }
            #pragma unroll
            for (int p = 0; p < 2; ++p) {
                int idx = p * 256 + tid;
                int row = idx >> 3;
                int cg  = idx & 7;
                uint4 v = *(const uint4*)&Wt[(size_t)(256 + row) * 256 + k0 + cg * 8];
                *(uint4*)&Bl[row * 72 + cg * 8] = v;
            }
            __syncthreads();

            #pragma unroll
            for (int ks = 0; ks < 64; ks += 32) {
                short8 bfr[2];
                #pragma unroll
                for (int s = 0; s < 2; ++s)
                    bfr[s] = *(short8*)&Bl[(wc * 32 + s * 16 + l15) * 72 + ks + quad * 8];
                #pragma unroll
                for (int t = 0; t < 4; ++t) {
                    short8 afr = *(short8*)&Al[(wr * 64 + t * 16 + l15) * 72 + ks + quad * 8];
                    #pragma unroll
                    for (int s = 0; s < 2; ++s)
                        acc[t][s] = __builtin_amdgcn_mfma_f32_16x16x32_bf16(afr, bfr[s], acc[t][s], 0, 0, 0);
                }
            }
            __syncthreads();
        }

        #pragma unroll
        for (int t = 0; t < 4; ++t) {
            #pragma unroll
            for (int s = 0; s < 2; ++s) {
                int c_local = wc * 32 + s * 16 + l15;
                #pragma unroll
                for (int reg = 0; reg < 4; ++reg) {
                    int m = m0 + wr * 64 + t * 16 + quad * 4 + reg;
                    if (m < nrows)
                        qk[(size_t)m * 64 + c_local] = acc[t][s][reg];
                }
            }
        }
    }
}

// -----------------------------------------------------------------------------
// K3: agg (R6 best config). One wave per dst node; degree <= 64.
// -----------------------------------------------------------------------------
__global__ __launch_bounds__(256) void agg_kernel(const unsigned short* __restrict__ zb,
                                                  const float* __restrict__ qk,
                                                  const float* __restrict__ coeff,
                                                  const unsigned int* __restrict__ slots,
                                                  const int* __restrict__ counts,
                                                  float* __restrict__ out,
                                                  int n_nodes) {
    __shared__ float cf[128];
    __shared__ float4 gsh[4][64];
    __shared__ int    ssh[4][64];
    if (threadIdx.x < 128) cf[threadIdx.x] = coeff[threadIdx.x];
    __syncthreads();

    int wv   = threadIdx.x >> 6;
    int n    = blockIdx.x * 4 + wv;
    int lane = threadIdx.x & 63;
    if (n >= n_nodes) return;

    int cnt = counts[n];
    if (cnt > SLOT_CAP) cnt = SLOT_CAP;
    const unsigned int* sl = slots + (size_t)n * SLOT_CAP;

    // ---- pass A
    float e0 = 0.f, e1 = 0.f, e2 = 0.f, e3 = 0.f;
    int s_edge = 0, r_edge = 0;
    if (lane < cnt) {
        unsigned p = sl[lane];
        s_edge = (int)(p & 0xFFFFFu);
        r_edge = (int)(p >> 20);
        float4 q  = *(const float4*)&qk[(size_t)s_edge * 64 + r_edge * 4];
        float4 kv = *(const float4*)&qk[(size_t)n * 64 + 32 + r_edge * 4];
        float l0 = q.x + kv.x, l1 = q.y + kv.y, l2 = q.z + kv.z, l3 = q.w + kv.w;
        l0 = (l0 > 0.f) ? l0 : LRELU * l0;
        l1 = (l1 > 0.f) ? l1 : LRELU * l1;
        l2 = (l2 > 0.f) ? l2 : LRELU * l2;
        l3 = (l3 > 0.f) ? l3 : LRELU * l3;
        e0 = __expf(l0); e1 = __expf(l1); e2 = __expf(l2); e3 = __expf(l3);
    }
    float d0 = e0, d1 = e1, d2 = e2, d3 = e3;
    #pragma unroll
    for (int off = 32; off; off >>= 1) {
        d0 += __shfl_xor(d0, off);
        d1 += __shfl_xor(d1, off);
        d2 += __shfl_xor(d2, off);
        d3 += __shfl_xor(d3, off);
    }
    if (lane < cnt) {
        float a0 = e0 * ((d0 > 0.f) ? 0.25f / d0 : 0.f);
        float a1 = e1 * ((d1 > 0.f) ? 0.25f / d1 : 0.f);
        float a2 = e2 * ((d2 > 0.f) ? 0.25f / d2 : 0.f);
        float a3 = e3 * ((d3 > 0.f) ? 0.25f / d3 : 0.f);
        const float* c0 = &cf[(r_edge * 4 + 0) * 4];
        const float* c1 = &cf[(r_edge * 4 + 1) * 4];
        const float* c2 = &cf[(r_edge * 4 + 2) * 4];
        const float* c3 = &cf[(r_edge * 4 + 3) * 4];
        float4 g4;
        g4.x = a0 * c0[0] + a1 * c1[0] + a2 * c2[0] + a3 * c3[0];
        g4.y = a0 * c0[1] + a1 * c1[1] + a2 * c2[1] + a3 * c3[1];
        g4.z = a0 * c0[2] + a1 * c1[2] + a2 * c2[2] + a3 * c3[2];
        g4.w = a0 * c0[3] + a1 * c1[3] + a2 * c2[3] + a3 * c3[3];
        gsh[wv][lane] = g4;
        ssh[wv][lane] = s_edge;
    }
    // wave-private LDS region: no barrier needed

    // ---- pass B
    int es = lane >> 3;
    int g  = lane & 7;
    float acc[4][2];
    #pragma unroll
    for (int v = 0; v < 4; ++v) { acc[v][0] = 0.f; acc[v][1] = 0.f; }

    for (int base = 0; base < cnt; base += 8) {
        int i = base + es;
        if (i < cnt) {
            float4 g4 = gsh[wv][i];
            int s = ssh[wv][i];
            const unsigned short* zr = zb + (size_t)s * 256 + g * 8;
            #pragma unroll
            for (int v = 0; v < 4; ++v) {
                uint4 z4 = *(const uint4*)(zr + v * 64);
                acc[v][0] += g4.x * bf2f_lo(z4.x) + g4.y * bf2f_hi(z4.x) +
                             g4.z * bf2f_lo(z4.y) + g4.w * bf2f_hi(z4.y);
                acc[v][1] += g4.x * bf2f_lo(z4.z) + g4.y * bf2f_hi(z4.z) +
                             g4.z * bf2f_lo(z4.w) + g4.w * bf2f_hi(z4.w);
            }
        }
    }

    #pragma unroll
    for (int v = 0; v < 4; ++v) {
        #pragma unroll
        for (int j = 0; j < 2; ++j) {
            acc[v][j] += __shfl_xor(acc[v][j], 8);
            acc[v][j] += __shfl_xor(acc[v][j], 16);
            acc[v][j] += __shfl_xor(acc[v][j], 32);
        }
    }
    if (es == 0) {
        #pragma unroll
        for (int v = 0; v < 4; ++v) {
            float2 o = make_float2(acc[v][0], acc[v][1]);
            *(float2*)&out[(size_t)n * 64 + v * 16 + g * 2] = o;
        }
    }
}

// -----------------------------------------------------------------------------
extern "C" void kernel_launch(void* const* d_in, const int* in_sizes, int n_in,
                              void* d_out, int out_size, void* d_ws, size_t ws_size,
                              hipStream_t stream) {
    const float* x      = (const float*)d_in[0];
    const float* basis  = (const float*)d_in[1];
    const float* coeff  = (const float*)d_in[2];
    const float* attn_q = (const float*)d_in[3];
    const float* attn_k = (const float*)d_in[4];
    const int*   src    = (const int*)d_in[5];
    const int*   dst    = (const int*)d_in[6];
    const int*   rel    = (const int*)d_in[7];
    float* out = (float*)d_out;

    const int n_nodes = in_sizes[0] / F_IN;   // 20000
    const int E       = in_sizes[5];          // 320000

    char* ws = (char*)d_ws;
    size_t off = 0;
    auto alloc = [&](size_t bytes) -> void* {
        void* p = ws + off;
        off += bytes;
        off = (off + 255) & ~(size_t)255;
        return p;
    };
    unsigned short* xb   = (unsigned short*)alloc((size_t)n_nodes * 256 * 2);   // 10.2 MB
    unsigned short* Wt   = (unsigned short*)alloc((size_t)320 * 256 * 2);       // 160 KB
    unsigned short* zb   = (unsigned short*)alloc((size_t)n_nodes * 256 * 2);   // 10.2 MB
    float* qk            = (float*)alloc((size_t)n_nodes * 64 * 4);             // 5.1 MB
    unsigned int* slots  = (unsigned int*)alloc((size_t)n_nodes * SLOT_CAP * 4);// 5.1 MB
    int* counts          = (int*)alloc((size_t)n_nodes * 4);

    const int total4 = n_nodes * 64;
    const int n_cast_blocks = (total4 + 255) / 256;

    prep_all<<<n_cast_blocks + C_TOT, 256, 0, stream>>>(
        x, xb, total4, counts, n_nodes, basis, coeff, attn_q, attn_k, Wt, n_cast_blocks);

    dim3 g2((n_nodes + 127) / 128, 4);
    gemm_scatter<<<g2, 256, 0, stream>>>(xb, Wt, zb, qk, src, dst, rel, counts, slots,
                                         n_nodes, E);

    agg_kernel<<<(n_nodes + 3) / 4, 256, 0, stream>>>(zb, qk, coeff, slots, counts, out, n_nodes);
}